// Round 9
// baseline (441.074 us; speedup 1.0000x reference)
//
#include <hip/hip_runtime.h>
#include <hip/hip_bf16.h>
#include <stdint.h>
#include <stddef.h>

#define SEQ 2048
#define DIM 2048
#define NH 16
#define HD 128
#define BSZ 2
#define MTOT (BSZ*SEQ)   // 4096
#define KDIM 2048
#define NTL (KDIM/32)    // 64 K-tiles of BK=32

typedef __bf16 bf16;
typedef __attribute__((ext_vector_type(4))) __bf16 bf16x4;
typedef __attribute__((ext_vector_type(8))) __bf16 bf16x8;
typedef __attribute__((ext_vector_type(4))) float f32x4;

#define MFMA16(a,b,c) __builtin_amdgcn_mfma_f32_16x16x32_bf16((a),(b),(c),0,0,0)

__device__ __forceinline__ void glds16(const void* g, void* l) {
  __builtin_amdgcn_global_load_lds((__attribute__((address_space(1))) void*)(g),
                                   (__attribute__((address_space(3))) void*)(l),
                                   16, 0, 0);
}

__device__ __forceinline__ f32x4 f4zero() { f32x4 v = {0.f, 0.f, 0.f, 0.f}; return v; }

__device__ __forceinline__ uint32_t bpack(float a, float b) {
  uint16_t au = __builtin_bit_cast(uint16_t, (bf16)a);
  uint16_t bu = __builtin_bit_cast(uint16_t, (bf16)b);
  return (uint32_t)au | ((uint32_t)bu << 16);
}

// ---------------------------------------------------------------------------
// cast x (fp32) -> bf16, 4 elements/thread, exact grid
// ---------------------------------------------------------------------------
__global__ void cast_x_bf16(const float* __restrict__ in, bf16* __restrict__ out) {
  size_t i = (size_t)blockIdx.x * blockDim.x + threadIdx.x;
  float4 v = ((const float4*)in)[i];
  bf16x4 ov;
  ov.x = (bf16)v.x; ov.y = (bf16)v.y; ov.z = (bf16)v.z; ov.w = (bf16)v.w;
  ((bf16x4*)out)[i] = ov;
}

// ---------------------------------------------------------------------------
// All 4 weights W [K][N] fp32 -> WT [N][K] bf16 in ONE kernel (z = which W).
// ---------------------------------------------------------------------------
__global__ void transpose_w4(const float* __restrict__ wq, const float* __restrict__ wk,
                             const float* __restrict__ wv, const float* __restrict__ wo,
                             bf16* __restrict__ wT) {
  __shared__ float tile[64][65];
  const float* W = (blockIdx.z == 0) ? wq : (blockIdx.z == 1) ? wk
                  : (blockIdx.z == 2) ? wv : wo;
  bf16* WT = wT + (size_t)blockIdx.z * DIM * DIM;
  const int bk = blockIdx.x, bn = blockIdx.y;
  const int tid = threadIdx.x;
  const int tc = tid & 15, tr = tid >> 4;  // 16 x 16
#pragma unroll
  for (int p = 0; p < 4; ++p) {
    int k = tr + p * 16;
    float4 v = *(const float4*)(W + (size_t)(bk * 64 + k) * DIM + bn * 64 + tc * 4);
    tile[k][tc * 4 + 0] = v.x;
    tile[k][tc * 4 + 1] = v.y;
    tile[k][tc * 4 + 2] = v.z;
    tile[k][tc * 4 + 3] = v.w;
  }
  __syncthreads();
#pragma unroll
  for (int p = 0; p < 4; ++p) {
    int n = tr + p * 16;
    bf16x4 ov;
    ov.x = (bf16)tile[tc * 4 + 0][n];
    ov.y = (bf16)tile[tc * 4 + 1][n];
    ov.z = (bf16)tile[tc * 4 + 2][n];
    ov.w = (bf16)tile[tc * 4 + 3][n];
    *(bf16x4*)(WT + (size_t)(bn * 64 + n) * DIM + bk * 64 + tc * 4) = ov;
  }
}

// ---------------------------------------------------------------------------
// gemm9: phase-scheduled GEMM (best verified: 173 us QKV, 592 TF).
// C[4096][N] = A[4096][2048] @ BT[N][2048]^T, bf16 in, BM=256 BN=128 BK=32.
// 512 threads = 8 waves (4M x 2N), per-wave 64x64 output. 4-slot LDS ring
// (96KB). Phase: {8 ds_read | stage p+3 | barrier | 16 MFMA | vmcnt | barrier}.
// MODE 0: fp32 store. MODE 1: fused QKV (N=6144; seg0 Q-RoPE, seg1 K-RoPE,
// seg2 V^T (b,h,d,s)).
// ---------------------------------------------------------------------------
template<int MODE>
__global__ __launch_bounds__(512, 2)
void gemm9(const bf16* __restrict__ A, const bf16* __restrict__ BT,
           float* __restrict__ out0,
           bf16* __restrict__ qb, bf16* __restrict__ kbuf, bf16* __restrict__ vT,
           const float* __restrict__ cosT, const float* __restrict__ sinT)
{
  extern __shared__ uint8_t smem[];  // 4 x 24KB
  const int tid = threadIdx.x;
  const int lane = tid & 63, w = tid >> 6;
  const int l15 = lane & 15, h4 = lane >> 4;
  const int wr = w & 3, wc = w >> 2;   // 4 x 2 waves

  // T1: bijective chunked XCD swizzle (grid % 8 == 0)
  const int f = blockIdx.x;
  const int cpx = gridDim.x >> 3;
  const int swz = (f & 7) * cpx + (f >> 3);
  const int bm = swz & 15;
  const int bn = swz >> 4;

  const size_t strideB = (size_t)KDIM * 2;
  const uint8_t* Ab = (const uint8_t*)A + (size_t)(bm * 256) * strideB;
  const uint8_t* Bb = (const uint8_t*)BT + (size_t)(bn * 128) * strideB;

  const int r0 = tid >> 2;   // 0..127
  const int g0 = tid & 3;

  // stage K-tile t into slot t&3: 3 glds/wave (A c0, A c1, B)
  auto stage = [&](int t) {
    uint8_t* slot = smem + (t & 3) * 24576;
    const int k0 = t * 64;
    int row = r0;
    glds16(Ab + (size_t)row * strideB + k0 + ((g0 ^ ((row >> 1) & 3)) << 4),
           slot + tid * 16);
    row = 128 + r0;
    glds16(Ab + (size_t)row * strideB + k0 + ((g0 ^ ((row >> 1) & 3)) << 4),
           slot + 8192 + tid * 16);
    row = r0;
    glds16(Bb + (size_t)row * strideB + k0 + ((g0 ^ ((row >> 1) & 3)) << 4),
           slot + 16384 + tid * 16);
  };

  f32x4 acc[4][4];
#pragma unroll
  for (int m = 0; m < 4; ++m)
#pragma unroll
    for (int n = 0; n < 4; ++n) acc[m][n] = f4zero();

  // prologue: 3 tiles in flight, wait for tile 0 (oldest 3 loads)
  stage(0); stage(1); stage(2);
  asm volatile("s_waitcnt vmcnt(6)" ::: "memory");
  __builtin_amdgcn_s_barrier();
  asm volatile("" ::: "memory");

#pragma unroll 1
  for (int p = 0; p < NTL; ++p) {
    const uint8_t* sa = smem + (p & 3) * 24576;
    const uint8_t* sb = sa + 16384;
    bf16x8 aF[4], bF[4];
#pragma unroll
    for (int mf = 0; mf < 4; ++mf) {
      int row = wr * 64 + mf * 16 + l15;
      aF[mf] = *(const bf16x8*)(sa + row * 64 + ((h4 ^ ((row >> 1) & 3)) << 4));
    }
#pragma unroll
    for (int nf = 0; nf < 4; ++nf) {
      int row = wc * 64 + nf * 16 + l15;
      bF[nf] = *(const bf16x8*)(sb + row * 64 + ((h4 ^ ((row >> 1) & 3)) << 4));
    }
    if (p + 3 < NTL) stage(p + 3);  // writes slot (p-1)&3: reads done at p-1 end

    asm volatile("" ::: "memory");
    __builtin_amdgcn_s_barrier();
    asm volatile("" ::: "memory");

    __builtin_amdgcn_s_setprio(1);
#pragma unroll
    for (int mf = 0; mf < 4; ++mf)
#pragma unroll
      for (int nf = 0; nf < 4; ++nf)
        acc[mf][nf] = MFMA16(aF[mf], bF[nf], acc[mf][nf]);
    __builtin_amdgcn_s_setprio(0);

    // counted wait gating next phase's ds_read of tile p+1
    if (p < NTL - 3)       { asm volatile("s_waitcnt vmcnt(6)" ::: "memory"); }
    else if (p == NTL - 3) { asm volatile("s_waitcnt vmcnt(3)" ::: "memory"); }
    else if (p == NTL - 2) { asm volatile("s_waitcnt vmcnt(0)" ::: "memory"); }
    asm volatile("" ::: "memory");
    __builtin_amdgcn_s_barrier();
    asm volatile("" ::: "memory");
  }

  // ---- epilogue
  const int row0 = bm * 256 + wr * 64;
  const int col0 = bn * 128 + wc * 64;
#pragma unroll
  for (int mf = 0; mf < 4; ++mf) {
#pragma unroll
    for (int nf = 0; nf < 4; ++nf) {
#pragma unroll
      for (int r = 0; r < 4; ++r) {
        int row = row0 + mf * 16 + h4 * 4 + r;
        int col = col0 + nf * 16 + l15;
        float v = acc[mf][nf][r];
        if constexpr (MODE == 0) {
          out0[(size_t)row * DIM + col] = v;
        } else {
          int seg = col >> 11;
          int ccol = col & (DIM - 1);
          if (seg < 2) {  // Q or K: RoPE
            float v2 = __shfl_xor(v, 1);
            int s = row & (SEQ - 1);
            int jidx = (ccol & (HD - 1)) >> 1;
            float c = cosT[s * (HD / 2) + jidx];
            float sn = sinT[s * (HD / 2) + jidx];
            float o = (col & 1) ? fmaf(v2, sn, v * c) : fmaf(v, c, -(v2 * sn));
            bf16* dst = (seg == 0) ? qb : kbuf;
            dst[(size_t)row * DIM + ccol] = (bf16)o;
          } else {        // V: transposed (b,h,d,s) store
            int hh = ccol >> 7, d = ccol & (HD - 1);
            int bb = row >> 11, s = row & (SEQ - 1);
            vT[((size_t)(bb * NH + hh) * HD + d) * SEQ + s] = (bf16)v;
          }
        }
      }
    }
  }
}

// ---------------------------------------------------------------------------
// Flash attention, swapped-operand form. R3-VERIFIED grid dim3(16,16,2):
// pr = blockIdx.x, h = blockIdx.y, b = blockIdx.z (the XCD-grouped flat
// decode of R5-R7 thrashed L2 at exactly-capacity: 4 groups x 1MB = 4MB/XCD).
// Block pr processes q-tiles pr and (31-pr): 33 KV tiles each -> balanced.
// ---------------------------------------------------------------------------
__global__ __launch_bounds__(256, 2)
void flash_attn(const bf16* __restrict__ Q, const bf16* __restrict__ Kg,
                const bf16* __restrict__ VT, bf16* __restrict__ O)
{
  __shared__ __align__(16) bf16 Ks[2][64 * 128];   // [key][d], swizzled
  __shared__ __align__(16) bf16 Vs[2][128 * 64];   // [d][key], swizzled

  const int pr = blockIdx.x, h = blockIdx.y, b = blockIdx.z;

  const int tid = threadIdx.x, lane = tid & 63, w = tid >> 6;
  const int l15 = lane & 15, h4 = lane >> 4;
  const bool hhalf = ((h4 >> 1) & 1) != 0;

  const float scale = 0.08838834764831845f;  // 1/sqrt(128)
  const uint8_t* kgb = (const uint8_t*)Kg + ((size_t)(b * SEQ) * DIM + h * HD) * 2;
  const uint8_t* vgb = (const uint8_t*)VT + ((size_t)(b * NH + h) * HD * SEQ) * 2;

  auto stageKV = [&](int buf, int t) {
    const uint8_t* ksrc = kgb + (size_t)t * 64 * (DIM * 2);
    const uint8_t* vsrc = vgb + (size_t)t * 64 * 2;
#pragma unroll
    for (int j = 0; j < 4; ++j) {
      int chunk = w * 256 + j * 64 + lane;
      int key = chunk >> 4, ck = chunk & 15;
      int jk = (ck * 16) ^ ((key & 7) << 4);
      glds16(ksrc + (size_t)key * (DIM * 2) + jk,
             (uint8_t*)&Ks[buf][0] + (w * 256 + j * 64) * 16);
      int d = chunk >> 3, cv = chunk & 7;
      int jv = (cv * 16) ^ ((d & 7) << 4);
      glds16(vsrc + (size_t)d * (SEQ * 2) + jv,
             (uint8_t*)&Vs[buf][0] + (w * 256 + j * 64) * 16);
    }
  };

#pragma unroll 1
  for (int qsel = 0; qsel < 2; ++qsel) {
    const int qt = qsel ? (SEQ / 64 - 1 - pr) : pr;
    const int q0 = qt * 64;
    const int qrow = q0 + w * 16 + l15;

    // Q fragment (registers): lane holds Q[qrow][kk*32 + h4*8 .. +7]
    const bf16* qbase = Q + ((size_t)(b * SEQ + qrow)) * DIM + h * HD;
    bf16x8 aQ[4];
#pragma unroll
    for (int kk = 0; kk < 4; ++kk)
      aQ[kk] = *(const bf16x8*)(qbase + kk * 32 + h4 * 8);

    f32x4 o[8];
#pragma unroll
    for (int i = 0; i < 8; ++i) o[i] = f4zero();
    float mrun = -1e30f, lrun = 0.0f;

    stageKV(0, 0);
    __syncthreads();

#pragma unroll 1
    for (int t = 0; t <= qt; ++t) {
      const int cur = t & 1;
      if (t < qt) stageKV(cur ^ 1, t + 1);

      // ---- S^T = K Q^T : per lane S[key = kb*16 + h4*4 + r][q = l15]
      f32x4 S[4];
      __builtin_amdgcn_s_setprio(1);
#pragma unroll
      for (int kb = 0; kb < 4; ++kb) {
        f32x4 a = f4zero();
        int key = kb * 16 + l15;
        int swzk = (key & 7) << 4;
#pragma unroll
        for (int kk = 0; kk < 4; ++kk) {
          bf16x8 aK = *(const bf16x8*)((const uint8_t*)&Ks[cur][0] + key * 256 +
                                       (((kk * 32 + h4 * 8) * 2) ^ swzk));
          a = MFMA16(aK, aQ[kk], a);
        }
        S[kb] = a;
      }
      __builtin_amdgcn_s_setprio(0);

      // ---- scale (+ causal mask on the diagonal tile only)
      if (t == qt) {
#pragma unroll
        for (int kb = 0; kb < 4; ++kb)
#pragma unroll
          for (int r = 0; r < 4; ++r) {
            int key = q0 + kb * 16 + h4 * 4 + r;
            float sv = S[kb][r] * scale;
            S[kb][r] = (key > qrow) ? -1e9f : sv;
          }
      } else {
#pragma unroll
        for (int kb = 0; kb < 4; ++kb)
#pragma unroll
          for (int r = 0; r < 4; ++r) S[kb][r] *= scale;
      }

      // ---- per-lane online softmax for q-row = l15 (64 keys over h4 group)
      float pmax = S[0][0];
#pragma unroll
      for (int kb = 0; kb < 4; ++kb)
#pragma unroll
        for (int r = 0; r < 4; ++r) pmax = fmaxf(pmax, S[kb][r]);
      pmax = fmaxf(pmax, __shfl_xor(pmax, 16));
      pmax = fmaxf(pmax, __shfl_xor(pmax, 32));
      float mnew = fmaxf(mrun, pmax);
      float corr = __expf(mrun - mnew);
      float p[4][4];
      float psum = 0.f;
#pragma unroll
      for (int kb = 0; kb < 4; ++kb)
#pragma unroll
        for (int r = 0; r < 4; ++r) {
          float pv = __expf(S[kb][r] - mnew);
          p[kb][r] = pv;
          psum += pv;
        }
      psum += __shfl_xor(psum, 16);
      psum += __shfl_xor(psum, 32);
      lrun = lrun * corr + psum;
      mrun = mnew;
#pragma unroll
      for (int i = 0; i < 8; ++i) o[i] *= corr;

      // ---- pack P to bf16 pairs: pk[kb] = {p[kb][0..1], p[kb][2..3]}
      uint32_t pk[4][2];
#pragma unroll
      for (int kb = 0; kb < 4; ++kb) {
        pk[kb][0] = bpack(p[kb][0], p[kb][1]);
        pk[kb][1] = bpack(p[kb][2], p[kb][3]);
      }

      // ---- butterfly: build P^T B-fragments, k = kb2*32 + h4*8 + j
      bf16x8 pB[2];
#pragma unroll
      for (int kb2 = 0; kb2 < 2; ++kb2) {
        uint32_t s0a = hhalf ? pk[kb2 * 2 + 1][0] : pk[kb2 * 2][0];
        uint32_t s0b = hhalf ? pk[kb2 * 2 + 1][1] : pk[kb2 * 2][1];
        uint32_t s1a = hhalf ? pk[kb2 * 2][0] : pk[kb2 * 2 + 1][0];
        uint32_t s1b = hhalf ? pk[kb2 * 2][1] : pk[kb2 * 2 + 1][1];
        uint32_t e16a = __shfl_xor(s0a, 16), e16b = __shfl_xor(s0b, 16);
        uint32_t e32a = __shfl_xor(s1a, 32), e32b = __shfl_xor(s1b, 32);
        uint32_t e48a = __shfl_xor(s1a, 48), e48b = __shfl_xor(s1b, 48);
        uint32_t lo0 = (h4 == 0) ? s0a : (h4 == 1) ? e48a : (h4 == 2) ? e32a : e16a;
        uint32_t lo1 = (h4 == 0) ? s0b : (h4 == 1) ? e48b : (h4 == 2) ? e32b : e16b;
        uint32_t hi0 = (h4 == 0) ? e16a : (h4 == 1) ? e32a : (h4 == 2) ? e48a : s0a;
        uint32_t hi1 = (h4 == 0) ? e16b : (h4 == 1) ? e32b : (h4 == 2) ? e48b : s0b;
        uint4 u = make_uint4(lo0, lo1, hi0, hi1);
        pB[kb2] = __builtin_bit_cast(bf16x8, u);
      }

      // ---- O^T += V^T P^T : lane accumulates O[q=l15][d = db*16 + h4*4 + r]
      __builtin_amdgcn_s_setprio(1);
#pragma unroll
      for (int db = 0; db < 8; ++db) {
        int drow = db * 16 + l15;
        int swzv = (drow & 7) << 4;
#pragma unroll
        for (int kb2 = 0; kb2 < 2; ++kb2) {
          bf16x8 aV = *(const bf16x8*)((const uint8_t*)&Vs[cur][0] + drow * 128 +
                                       (((kb2 * 32 + h4 * 8) * 2) ^ swzv));
          o[db] = MFMA16(aV, pB[kb2], o[db]);
        }
      }
      __builtin_amdgcn_s_setprio(0);

      __syncthreads();
    }

    // ---- epilogue: O[b, qrow, h, d] = o / l  (4 bf16 = 8B per db)
    float inv = 1.0f / lrun;
    bf16* obase = O + ((size_t)(b * SEQ + qrow)) * DIM + h * HD;
#pragma unroll
    for (int db = 0; db < 8; ++db) {
      uint32_t w0 = bpack(o[db][0] * inv, o[db][1] * inv);
      uint32_t w1 = bpack(o[db][2] * inv, o[db][3] * inv);
      uint2 st = make_uint2(w0, w1);
      *(uint2*)(obase + db * 16 + h4 * 4) = st;
    }
  }
}

// ---------------------------------------------------------------------------
extern "C" void kernel_launch(void* const* d_in, const int* in_sizes, int n_in,
                              void* d_out, int out_size, void* d_ws, size_t ws_size,
                              hipStream_t stream)
{
  const float* x    = (const float*)d_in[0];
  const float* fcos = (const float*)d_in[1];
  const float* fsin = (const float*)d_in[2];
  // d_in[3] = mask (reimplemented as causal test)
  const float* wq   = (const float*)d_in[4];
  const float* wk   = (const float*)d_in[5];
  const float* wv   = (const float*)d_in[6];
  const float* wo   = (const float*)d_in[7];

  uint8_t* ws = (uint8_t*)d_ws;
  const size_t SZ_XB = (size_t)MTOT * DIM * 2;  // 16 MB bf16 activations
  const size_t SZ_WT = (size_t)DIM * DIM * 2;   // 8 MB bf16 weight

  bf16* xb    = (bf16*)(ws);
  bf16* wqT   = (bf16*)(ws + SZ_XB);            // wq/wk/wv/wo T contiguous
  bf16* woT   = (bf16*)(ws + SZ_XB + 3 * SZ_WT);
  bf16* qb    = (bf16*)(ws + SZ_XB + 4 * SZ_WT);
  bf16* kb    = (bf16*)(ws + 2 * SZ_XB + 4 * SZ_WT);
  bf16* vT    = (bf16*)(ws + 3 * SZ_XB + 4 * SZ_WT);
  bf16* attnb = xb;  // xb dead after QKV projection; reuse for attention out

  // allow 96 KiB dynamic LDS (idempotent, not a stream op)
  hipFuncSetAttribute((const void*)gemm9<1>,
                      hipFuncAttributeMaxDynamicSharedMemorySize, 98304);
  hipFuncSetAttribute((const void*)gemm9<0>,
                      hipFuncAttributeMaxDynamicSharedMemorySize, 98304);

  cast_x_bf16<<<(MTOT * DIM) / (256 * 4), 256, 0, stream>>>(x, xb);
  transpose_w4<<<dim3(DIM / 64, DIM / 64, 4), 256, 0, stream>>>(wq, wk, wv, wo, wqT);

  // fused QKV: C[4096][6144]; grid 16*48 = 768
  gemm9<1><<<768, 512, 98304, stream>>>(xb, wqT, nullptr, qb, kb, vT, fcos, fsin);

  flash_attn<<<dim3(SEQ / 128, NH, BSZ), 256, 0, stream>>>(qb, kb, vT, attnb);

  // WO: C[4096][2048] fp32; grid 16*16 = 256
  gemm9<0><<<256, 512, 98304, stream>>>(attnb, woT, (float*)d_out,
                                        nullptr, nullptr, nullptr, nullptr, nullptr);
}

// Round 10
// 411.353 us; speedup vs baseline: 1.0723x; 1.0723x over previous
//
#include <hip/hip_runtime.h>
#include <hip/hip_bf16.h>
#include <stdint.h>
#include <stddef.h>

#define SEQ 2048
#define DIM 2048
#define NH 16
#define HD 128
#define BSZ 2
#define MTOT (BSZ*SEQ)   // 4096
#define KDIM 2048
#define NTL (KDIM/32)    // 64 K-tiles of BK=32

typedef __bf16 bf16;
typedef __attribute__((ext_vector_type(4))) __bf16 bf16x4;
typedef __attribute__((ext_vector_type(8))) __bf16 bf16x8;
typedef __attribute__((ext_vector_type(4))) float f32x4;

#define MFMA16(a,b,c) __builtin_amdgcn_mfma_f32_16x16x32_bf16((a),(b),(c),0,0,0)

__device__ __forceinline__ void glds16(const void* g, void* l) {
  __builtin_amdgcn_global_load_lds((__attribute__((address_space(1))) void*)(g),
                                   (__attribute__((address_space(3))) void*)(l),
                                   16, 0, 0);
}

__device__ __forceinline__ f32x4 f4zero() { f32x4 v = {0.f, 0.f, 0.f, 0.f}; return v; }

__device__ __forceinline__ uint32_t bpack(float a, float b) {
  uint16_t au = __builtin_bit_cast(uint16_t, (bf16)a);
  uint16_t bu = __builtin_bit_cast(uint16_t, (bf16)b);
  return (uint32_t)au | ((uint32_t)bu << 16);
}

// ---------------------------------------------------------------------------
// cast x (fp32) -> bf16, 4 elements/thread, exact grid
// ---------------------------------------------------------------------------
__global__ void cast_x_bf16(const float* __restrict__ in, bf16* __restrict__ out) {
  size_t i = (size_t)blockIdx.x * blockDim.x + threadIdx.x;
  float4 v = ((const float4*)in)[i];
  bf16x4 ov;
  ov.x = (bf16)v.x; ov.y = (bf16)v.y; ov.z = (bf16)v.z; ov.w = (bf16)v.w;
  ((bf16x4*)out)[i] = ov;
}

// ---------------------------------------------------------------------------
// All 4 weights W [K][N] fp32 -> WT [N][K] bf16 in ONE kernel (z = which W).
// ---------------------------------------------------------------------------
__global__ void transpose_w4(const float* __restrict__ wq, const float* __restrict__ wk,
                             const float* __restrict__ wv, const float* __restrict__ wo,
                             bf16* __restrict__ wT) {
  __shared__ float tile[64][65];
  const float* W = (blockIdx.z == 0) ? wq : (blockIdx.z == 1) ? wk
                  : (blockIdx.z == 2) ? wv : wo;
  bf16* WT = wT + (size_t)blockIdx.z * DIM * DIM;
  const int bk = blockIdx.x, bn = blockIdx.y;
  const int tid = threadIdx.x;
  const int tc = tid & 15, tr = tid >> 4;  // 16 x 16
#pragma unroll
  for (int p = 0; p < 4; ++p) {
    int k = tr + p * 16;
    float4 v = *(const float4*)(W + (size_t)(bk * 64 + k) * DIM + bn * 64 + tc * 4);
    tile[k][tc * 4 + 0] = v.x;
    tile[k][tc * 4 + 1] = v.y;
    tile[k][tc * 4 + 2] = v.z;
    tile[k][tc * 4 + 3] = v.w;
  }
  __syncthreads();
#pragma unroll
  for (int p = 0; p < 4; ++p) {
    int n = tr + p * 16;
    bf16x4 ov;
    ov.x = (bf16)tile[tc * 4 + 0][n];
    ov.y = (bf16)tile[tc * 4 + 1][n];
    ov.z = (bf16)tile[tc * 4 + 2][n];
    ov.w = (bf16)tile[tc * 4 + 3][n];
    *(bf16x4*)(WT + (size_t)(bn * 64 + n) * DIM + bk * 64 + tc * 4) = ov;
  }
}

// ---------------------------------------------------------------------------
// gemm9: phase-scheduled GEMM (verified structure; 592 TF aggregate).
// C[4096][2048] = A[4096][2048] @ BT[2048][2048]^T, BM=256 BN=128 BK=32.
// 512 threads = 8 waves (4M x 2N), per-wave 64x64 output. 4-slot LDS ring
// (96KB). Phase: {8 ds_read | stage p+3 | barrier | 16 MFMA | vmcnt | barrier}.
// Grid 16x16 = 256 blocks = exactly one CU round; separate launches per
// output so rocprof top-5 exposes every kernel (attribution round).
// SEG 0: Q-RoPE -> outb. SEG 1: K-RoPE -> outb. SEG 2: V^T (b,h,d,s) -> outb.
// SEG 3: fp32 -> out0.
// ---------------------------------------------------------------------------
template<int SEG>
__global__ __launch_bounds__(512, 2)
void gemm9(const bf16* __restrict__ A, const bf16* __restrict__ BT,
           float* __restrict__ out0, bf16* __restrict__ outb,
           const float* __restrict__ cosT, const float* __restrict__ sinT)
{
  extern __shared__ uint8_t smem[];  // 4 x 24KB
  const int tid = threadIdx.x;
  const int lane = tid & 63, w = tid >> 6;
  const int l15 = lane & 15, h4 = lane >> 4;
  const int wr = w & 3, wc = w >> 2;   // 4 x 2 waves

  // T1: bijective chunked XCD swizzle (grid % 8 == 0)
  const int f = blockIdx.x;
  const int cpx = gridDim.x >> 3;
  const int swz = (f & 7) * cpx + (f >> 3);
  const int bm = swz & 15;
  const int bn = swz >> 4;

  const size_t strideB = (size_t)KDIM * 2;
  const uint8_t* Ab = (const uint8_t*)A + (size_t)(bm * 256) * strideB;
  const uint8_t* Bb = (const uint8_t*)BT + (size_t)(bn * 128) * strideB;

  const int r0 = tid >> 2;   // 0..127
  const int g0 = tid & 3;

  // stage K-tile t into slot t&3: 3 glds/wave (A c0, A c1, B)
  auto stage = [&](int t) {
    uint8_t* slot = smem + (t & 3) * 24576;
    const int k0 = t * 64;
    int row = r0;
    glds16(Ab + (size_t)row * strideB + k0 + ((g0 ^ ((row >> 1) & 3)) << 4),
           slot + tid * 16);
    row = 128 + r0;
    glds16(Ab + (size_t)row * strideB + k0 + ((g0 ^ ((row >> 1) & 3)) << 4),
           slot + 8192 + tid * 16);
    row = r0;
    glds16(Bb + (size_t)row * strideB + k0 + ((g0 ^ ((row >> 1) & 3)) << 4),
           slot + 16384 + tid * 16);
  };

  f32x4 acc[4][4];
#pragma unroll
  for (int m = 0; m < 4; ++m)
#pragma unroll
    for (int n = 0; n < 4; ++n) acc[m][n] = f4zero();

  // prologue: 3 tiles in flight, wait for tile 0 (oldest 3 loads)
  stage(0); stage(1); stage(2);
  asm volatile("s_waitcnt vmcnt(6)" ::: "memory");
  __builtin_amdgcn_s_barrier();
  asm volatile("" ::: "memory");

#pragma unroll 1
  for (int p = 0; p < NTL; ++p) {
    const uint8_t* sa = smem + (p & 3) * 24576;
    const uint8_t* sb = sa + 16384;
    bf16x8 aF[4], bF[4];
#pragma unroll
    for (int mf = 0; mf < 4; ++mf) {
      int row = wr * 64 + mf * 16 + l15;
      aF[mf] = *(const bf16x8*)(sa + row * 64 + ((h4 ^ ((row >> 1) & 3)) << 4));
    }
#pragma unroll
    for (int nf = 0; nf < 4; ++nf) {
      int row = wc * 64 + nf * 16 + l15;
      bF[nf] = *(const bf16x8*)(sb + row * 64 + ((h4 ^ ((row >> 1) & 3)) << 4));
    }
    if (p + 3 < NTL) stage(p + 3);  // writes slot (p-1)&3: reads done at p-1 end

    asm volatile("" ::: "memory");
    __builtin_amdgcn_s_barrier();
    asm volatile("" ::: "memory");

    __builtin_amdgcn_s_setprio(1);
#pragma unroll
    for (int mf = 0; mf < 4; ++mf)
#pragma unroll
      for (int nf = 0; nf < 4; ++nf)
        acc[mf][nf] = MFMA16(aF[mf], bF[nf], acc[mf][nf]);
    __builtin_amdgcn_s_setprio(0);

    // counted wait gating next phase's ds_read of tile p+1
    if (p < NTL - 3)       { asm volatile("s_waitcnt vmcnt(6)" ::: "memory"); }
    else if (p == NTL - 3) { asm volatile("s_waitcnt vmcnt(3)" ::: "memory"); }
    else if (p == NTL - 2) { asm volatile("s_waitcnt vmcnt(0)" ::: "memory"); }
    asm volatile("" ::: "memory");
    __builtin_amdgcn_s_barrier();
    asm volatile("" ::: "memory");
  }

  // ---- epilogue
  const int row0 = bm * 256 + wr * 64;
  const int col0 = bn * 128 + wc * 64;
#pragma unroll
  for (int mf = 0; mf < 4; ++mf) {
#pragma unroll
    for (int nf = 0; nf < 4; ++nf) {
#pragma unroll
      for (int r = 0; r < 4; ++r) {
        int row = row0 + mf * 16 + h4 * 4 + r;
        int col = col0 + nf * 16 + l15;
        float v = acc[mf][nf][r];
        if constexpr (SEG == 3) {
          out0[(size_t)row * DIM + col] = v;
        } else if constexpr (SEG < 2) {  // Q or K: RoPE
          float v2 = __shfl_xor(v, 1);
          int s = row & (SEQ - 1);
          int jidx = (col & (HD - 1)) >> 1;
          float c = cosT[s * (HD / 2) + jidx];
          float sn = sinT[s * (HD / 2) + jidx];
          float o = (col & 1) ? fmaf(v2, sn, v * c) : fmaf(v, c, -(v2 * sn));
          outb[(size_t)row * DIM + col] = (bf16)o;
        } else {        // V: transposed (b,h,d,s) store
          int hh = col >> 7, d = col & (HD - 1);
          int bb = row >> 11, s = row & (SEQ - 1);
          outb[((size_t)(bb * NH + hh) * HD + d) * SEQ + s] = (bf16)v;
        }
      }
    }
  }
}

// ---------------------------------------------------------------------------
// Flash attention, swapped-operand form (R3-verified 89.9us body, grid
// dim3(16,16,2)). Block pr does q-tiles pr and (31-pr): 33 KV tiles each.
// ---------------------------------------------------------------------------
__global__ __launch_bounds__(256, 2)
void flash_attn(const bf16* __restrict__ Q, const bf16* __restrict__ Kg,
                const bf16* __restrict__ VT, bf16* __restrict__ O)
{
  __shared__ __align__(16) bf16 Ks[2][64 * 128];   // [key][d], swizzled
  __shared__ __align__(16) bf16 Vs[2][128 * 64];   // [d][key], swizzled

  const int pr = blockIdx.x, h = blockIdx.y, b = blockIdx.z;

  const int tid = threadIdx.x, lane = tid & 63, w = tid >> 6;
  const int l15 = lane & 15, h4 = lane >> 4;
  const bool hhalf = ((h4 >> 1) & 1) != 0;

  const float scale = 0.08838834764831845f;  // 1/sqrt(128)
  const uint8_t* kgb = (const uint8_t*)Kg + ((size_t)(b * SEQ) * DIM + h * HD) * 2;
  const uint8_t* vgb = (const uint8_t*)VT + ((size_t)(b * NH + h) * HD * SEQ) * 2;

  auto stageKV = [&](int buf, int t) {
    const uint8_t* ksrc = kgb + (size_t)t * 64 * (DIM * 2);
    const uint8_t* vsrc = vgb + (size_t)t * 64 * 2;
#pragma unroll
    for (int j = 0; j < 4; ++j) {
      int chunk = w * 256 + j * 64 + lane;
      int key = chunk >> 4, ck = chunk & 15;
      int jk = (ck * 16) ^ ((key & 7) << 4);
      glds16(ksrc + (size_t)key * (DIM * 2) + jk,
             (uint8_t*)&Ks[buf][0] + (w * 256 + j * 64) * 16);
      int d = chunk >> 3, cv = chunk & 7;
      int jv = (cv * 16) ^ ((d & 7) << 4);
      glds16(vsrc + (size_t)d * (SEQ * 2) + jv,
             (uint8_t*)&Vs[buf][0] + (w * 256 + j * 64) * 16);
    }
  };

#pragma unroll 1
  for (int qsel = 0; qsel < 2; ++qsel) {
    const int qt = qsel ? (SEQ / 64 - 1 - pr) : pr;
    const int q0 = qt * 64;
    const int qrow = q0 + w * 16 + l15;

    // Q fragment (registers): lane holds Q[qrow][kk*32 + h4*8 .. +7]
    const bf16* qbase = Q + ((size_t)(b * SEQ + qrow)) * DIM + h * HD;
    bf16x8 aQ[4];
#pragma unroll
    for (int kk = 0; kk < 4; ++kk)
      aQ[kk] = *(const bf16x8*)(qbase + kk * 32 + h4 * 8);

    f32x4 o[8];
#pragma unroll
    for (int i = 0; i < 8; ++i) o[i] = f4zero();
    float mrun = -1e30f, lrun = 0.0f;

    stageKV(0, 0);
    __syncthreads();

#pragma unroll 1
    for (int t = 0; t <= qt; ++t) {
      const int cur = t & 1;
      if (t < qt) stageKV(cur ^ 1, t + 1);

      // ---- S^T = K Q^T : per lane S[key = kb*16 + h4*4 + r][q = l15]
      f32x4 S[4];
      __builtin_amdgcn_s_setprio(1);
#pragma unroll
      for (int kb = 0; kb < 4; ++kb) {
        f32x4 a = f4zero();
        int key = kb * 16 + l15;
        int swzk = (key & 7) << 4;
#pragma unroll
        for (int kk = 0; kk < 4; ++kk) {
          bf16x8 aK = *(const bf16x8*)((const uint8_t*)&Ks[cur][0] + key * 256 +
                                       (((kk * 32 + h4 * 8) * 2) ^ swzk));
          a = MFMA16(aK, aQ[kk], a);
        }
        S[kb] = a;
      }
      __builtin_amdgcn_s_setprio(0);

      // ---- scale (+ causal mask on the diagonal tile only)
      if (t == qt) {
#pragma unroll
        for (int kb = 0; kb < 4; ++kb)
#pragma unroll
          for (int r = 0; r < 4; ++r) {
            int key = q0 + kb * 16 + h4 * 4 + r;
            float sv = S[kb][r] * scale;
            S[kb][r] = (key > qrow) ? -1e9f : sv;
          }
      } else {
#pragma unroll
        for (int kb = 0; kb < 4; ++kb)
#pragma unroll
          for (int r = 0; r < 4; ++r) S[kb][r] *= scale;
      }

      // ---- per-lane online softmax for q-row = l15 (64 keys over h4 group)
      float pmax = S[0][0];
#pragma unroll
      for (int kb = 0; kb < 4; ++kb)
#pragma unroll
        for (int r = 0; r < 4; ++r) pmax = fmaxf(pmax, S[kb][r]);
      pmax = fmaxf(pmax, __shfl_xor(pmax, 16));
      pmax = fmaxf(pmax, __shfl_xor(pmax, 32));
      float mnew = fmaxf(mrun, pmax);
      float corr = __expf(mrun - mnew);
      float p[4][4];
      float psum = 0.f;
#pragma unroll
      for (int kb = 0; kb < 4; ++kb)
#pragma unroll
        for (int r = 0; r < 4; ++r) {
          float pv = __expf(S[kb][r] - mnew);
          p[kb][r] = pv;
          psum += pv;
        }
      psum += __shfl_xor(psum, 16);
      psum += __shfl_xor(psum, 32);
      lrun = lrun * corr + psum;
      mrun = mnew;
#pragma unroll
      for (int i = 0; i < 8; ++i) o[i] *= corr;

      // ---- pack P to bf16 pairs: pk[kb] = {p[kb][0..1], p[kb][2..3]}
      uint32_t pk[4][2];
#pragma unroll
      for (int kb = 0; kb < 4; ++kb) {
        pk[kb][0] = bpack(p[kb][0], p[kb][1]);
        pk[kb][1] = bpack(p[kb][2], p[kb][3]);
      }

      // ---- butterfly: build P^T B-fragments, k = kb2*32 + h4*8 + j
      bf16x8 pB[2];
#pragma unroll
      for (int kb2 = 0; kb2 < 2; ++kb2) {
        uint32_t s0a = hhalf ? pk[kb2 * 2 + 1][0] : pk[kb2 * 2][0];
        uint32_t s0b = hhalf ? pk[kb2 * 2 + 1][1] : pk[kb2 * 2][1];
        uint32_t s1a = hhalf ? pk[kb2 * 2][0] : pk[kb2 * 2 + 1][0];
        uint32_t s1b = hhalf ? pk[kb2 * 2][1] : pk[kb2 * 2 + 1][1];
        uint32_t e16a = __shfl_xor(s0a, 16), e16b = __shfl_xor(s0b, 16);
        uint32_t e32a = __shfl_xor(s1a, 32), e32b = __shfl_xor(s1b, 32);
        uint32_t e48a = __shfl_xor(s1a, 48), e48b = __shfl_xor(s1b, 48);
        uint32_t lo0 = (h4 == 0) ? s0a : (h4 == 1) ? e48a : (h4 == 2) ? e32a : e16a;
        uint32_t lo1 = (h4 == 0) ? s0b : (h4 == 1) ? e48b : (h4 == 2) ? e32b : e16b;
        uint32_t hi0 = (h4 == 0) ? e16a : (h4 == 1) ? e32a : (h4 == 2) ? e48a : s0a;
        uint32_t hi1 = (h4 == 0) ? e16b : (h4 == 1) ? e32b : (h4 == 2) ? e48b : s0b;
        uint4 u = make_uint4(lo0, lo1, hi0, hi1);
        pB[kb2] = __builtin_bit_cast(bf16x8, u);
      }

      // ---- O^T += V^T P^T : lane accumulates O[q=l15][d = db*16 + h4*4 + r]
      __builtin_amdgcn_s_setprio(1);
#pragma unroll
      for (int db = 0; db < 8; ++db) {
        int drow = db * 16 + l15;
        int swzv = (drow & 7) << 4;
#pragma unroll
        for (int kb2 = 0; kb2 < 2; ++kb2) {
          bf16x8 aV = *(const bf16x8*)((const uint8_t*)&Vs[cur][0] + drow * 128 +
                                       (((kb2 * 32 + h4 * 8) * 2) ^ swzv));
          o[db] = MFMA16(aV, pB[kb2], o[db]);
        }
      }
      __builtin_amdgcn_s_setprio(0);

      __syncthreads();
    }

    // ---- epilogue: O[b, qrow, h, d] = o / l  (4 bf16 = 8B per db)
    float inv = 1.0f / lrun;
    bf16* obase = O + ((size_t)(b * SEQ + qrow)) * DIM + h * HD;
#pragma unroll
    for (int db = 0; db < 8; ++db) {
      uint32_t w0 = bpack(o[db][0] * inv, o[db][1] * inv);
      uint32_t w1 = bpack(o[db][2] * inv, o[db][3] * inv);
      uint2 st = make_uint2(w0, w1);
      *(uint2*)(obase + db * 16 + h4 * 4) = st;
    }
  }
}

// ---------------------------------------------------------------------------
extern "C" void kernel_launch(void* const* d_in, const int* in_sizes, int n_in,
                              void* d_out, int out_size, void* d_ws, size_t ws_size,
                              hipStream_t stream)
{
  const float* x    = (const float*)d_in[0];
  const float* fcos = (const float*)d_in[1];
  const float* fsin = (const float*)d_in[2];
  // d_in[3] = mask (reimplemented as causal test)
  const float* wq   = (const float*)d_in[4];
  const float* wk   = (const float*)d_in[5];
  const float* wv   = (const float*)d_in[6];
  const float* wo   = (const float*)d_in[7];

  uint8_t* ws = (uint8_t*)d_ws;
  const size_t SZ_XB = (size_t)MTOT * DIM * 2;  // 16 MB bf16 activations
  const size_t SZ_WT = (size_t)DIM * DIM * 2;   // 8 MB bf16 weight

  bf16* xb    = (bf16*)(ws);
  bf16* wqT   = (bf16*)(ws + SZ_XB);            // wq/wk/wv/wo T contiguous
  bf16* wkT   = (bf16*)(ws + SZ_XB + 1 * SZ_WT);
  bf16* wvT   = (bf16*)(ws + SZ_XB + 2 * SZ_WT);
  bf16* woT   = (bf16*)(ws + SZ_XB + 3 * SZ_WT);
  bf16* qb    = (bf16*)(ws + SZ_XB + 4 * SZ_WT);
  bf16* kb    = (bf16*)(ws + 2 * SZ_XB + 4 * SZ_WT);
  bf16* vT    = (bf16*)(ws + 3 * SZ_XB + 4 * SZ_WT);
  bf16* attnb = xb;  // xb dead after QKV projection; reuse for attention out

  // allow 96 KiB dynamic LDS (idempotent, not a stream op)
  hipFuncSetAttribute((const void*)gemm9<0>,
                      hipFuncAttributeMaxDynamicSharedMemorySize, 98304);
  hipFuncSetAttribute((const void*)gemm9<1>,
                      hipFuncAttributeMaxDynamicSharedMemorySize, 98304);
  hipFuncSetAttribute((const void*)gemm9<2>,
                      hipFuncAttributeMaxDynamicSharedMemorySize, 98304);
  hipFuncSetAttribute((const void*)gemm9<3>,
                      hipFuncAttributeMaxDynamicSharedMemorySize, 98304);

  cast_x_bf16<<<(MTOT * DIM) / (256 * 4), 256, 0, stream>>>(x, xb);
  transpose_w4<<<dim3(DIM / 64, DIM / 64, 4), 256, 0, stream>>>(wq, wk, wv, wo, wqT);

  // QKV as 3 separate launches (attribution: every kernel <= ~90us so the
  // rocprof top-5 exposes the true slowest dispatch). Grid 256 = 1 CU round.
  gemm9<0><<<256, 512, 98304, stream>>>(xb, wqT, nullptr, qb, fcos, fsin);
  gemm9<1><<<256, 512, 98304, stream>>>(xb, wkT, nullptr, kb, fcos, fsin);
  gemm9<2><<<256, 512, 98304, stream>>>(xb, wvT, nullptr, vT, nullptr, nullptr);

  flash_attn<<<dim3(SEQ / 128, NH, BSZ), 256, 0, stream>>>(qb, kb, vT, attnb);

  // WO: C[4096][2048] fp32; grid 256
  gemm9<3><<<256, 512, 98304, stream>>>(attnb, woT, (float*)d_out,
                                        nullptr, nullptr, nullptr);
}